// Round 2
// baseline (44.418 us; speedup 1.0000x reference)
//
#include <hip/hip_runtime.h>
#include <math.h>

// FeedForwardQuantum, analytically collapsed circuit:
// z_j = cos(theta_j) * cos(x.W1_j + b1_j)
// ex[w] = prod_{j<=w} z_j (w>=1); ex[0] = prod_{j=1..7} z_j
// out = relu(ex @ W2^T + b2)

constexpr int EMBED = 768;
constexpr int NQ    = 8;
constexpr int BLOCK = 256;           // 4 waves
constexpr int WAVES = 4;
constexpr int TPT   = 2;             // tokens processed CONCURRENTLY per wave
constexpr int TPB   = WAVES * TPT;   // 8 tokens per block

__global__ __launch_bounds__(BLOCK, 4) void ffq_kernel(
    const float* __restrict__ x,  const float* __restrict__ W1,
    const float* __restrict__ b1, const float* __restrict__ theta,
    const float* __restrict__ W2, const float* __restrict__ b2,
    float* __restrict__ out, int ntok)
{
    // W1 staged in LDS: 24 KB, float4 reads at 16B lane stride -> conflict-free
    __shared__ float4 w1s[NQ * EMBED / 4];

    const int tid = threadIdx.x;
    const float4* W14g = (const float4*)W1;
    #pragma unroll
    for (int i = tid; i < NQ * EMBED / 4; i += BLOCK) w1s[i] = W14g[i];
    __syncthreads();

    const int wave = tid >> 6;
    const int lane = tid & 63;
    const int t0 = (blockIdx.x * WAVES + wave) * TPT;
    if (t0 >= ntok) return;

    const float4* x40 = (const float4*)(x + (size_t)t0 * EMBED);
    const float4* x41 = (const float4*)(x + (size_t)(t0 + 1) * EMBED);

    // ---- GEMM1 partials (both tokens share each W1 read) ----
    float acc0[NQ], acc1[NQ];
    #pragma unroll
    for (int q = 0; q < NQ; ++q) { acc0[q] = 0.f; acc1[q] = 0.f; }

    #pragma unroll
    for (int k = 0; k < EMBED / 256; ++k) {      // 3 iterations
        const int idx = lane + 64 * k;           // float4 index
        const float4 xa = x40[idx];
        const float4 xb = x41[idx];
        #pragma unroll
        for (int q = 0; q < NQ; ++q) {
            const float4 w = w1s[q * (EMBED / 4) + idx];
            acc0[q] = fmaf(xa.x, w.x, fmaf(xa.y, w.y, fmaf(xa.z, w.z, fmaf(xa.w, w.w, acc0[q]))));
            acc1[q] = fmaf(xb.x, w.x, fmaf(xb.y, w.y, fmaf(xb.z, w.z, fmaf(xb.w, w.w, acc1[q]))));
        }
    }

    // ---- 64-lane butterfly; 16 independent chains interleave ----
    #pragma unroll
    for (int q = 0; q < NQ; ++q) {
        float v0 = acc0[q], v1 = acc1[q];
        #pragma unroll
        for (int off = 32; off; off >>= 1) {
            v0 += __shfl_xor(v0, off, 64);
            v1 += __shfl_xor(v1, off, 64);
        }
        acc0[q] = v0; acc1[q] = v1;
    }

    // ---- analytic circuit ----
    float z0[NQ], z1[NQ];
    #pragma unroll
    for (int q = 0; q < NQ; ++q) {
        const float ct = __cosf(theta[q]);       // uniform, cached
        const float bb = b1[q];
        z0[q] = ct * __cosf(acc0[q] + bb);
        z1[q] = ct * __cosf(acc1[q] + bb);
    }

    float e0[NQ], e1[NQ];
    {
        float p0 = z0[0], p1 = z1[0];
        #pragma unroll
        for (int q = 1; q < NQ; ++q) { p0 *= z0[q]; e0[q] = p0; p1 *= z1[q]; e1[q] = p1; }
        float s0 = z0[1], s1 = z1[1];
        #pragma unroll
        for (int q = 2; q < NQ; ++q) { s0 *= z0[q]; s1 *= z1[q]; }
        e0[0] = s0; e1[0] = s1;
    }

    // ---- GEMM2 + bias + relu (W2 L1-resident; per-lane reads 128B contiguous) ----
    const float4* W24 = (const float4*)W2;       // W2[e][0..7] = 2 float4 at 2*e
    const float4* b24 = (const float4*)b2;
    float4* o0 = (float4*)(out + (size_t)t0 * EMBED);
    float4* o1 = (float4*)(out + (size_t)(t0 + 1) * EMBED);

    #pragma unroll
    for (int k = 0; k < EMBED / 256; ++k) {
        const int idx = lane + 64 * k;           // float4 index; elements 4*idx..4*idx+3
        const float4 bb = b24[idx];
        const float bbv[4] = { bb.x, bb.y, bb.z, bb.w };
        float r0v[4], r1v[4];
        #pragma unroll
        for (int j = 0; j < 4; ++j) {
            const int e = 4 * idx + j;
            const float4 wa = W24[2 * e];
            const float4 wb = W24[2 * e + 1];
            float s0 = bbv[j], s1 = bbv[j];
            s0 = fmaf(e0[0], wa.x, fmaf(e0[1], wa.y, fmaf(e0[2], wa.z, fmaf(e0[3], wa.w, s0))));
            s0 = fmaf(e0[4], wb.x, fmaf(e0[5], wb.y, fmaf(e0[6], wb.z, fmaf(e0[7], wb.w, s0))));
            s1 = fmaf(e1[0], wa.x, fmaf(e1[1], wa.y, fmaf(e1[2], wa.z, fmaf(e1[3], wa.w, s1))));
            s1 = fmaf(e1[4], wb.x, fmaf(e1[5], wb.y, fmaf(e1[6], wb.z, fmaf(e1[7], wb.w, s1))));
            r0v[j] = fmaxf(s0, 0.f);
            r1v[j] = fmaxf(s1, 0.f);
        }
        o0[idx] = make_float4(r0v[0], r0v[1], r0v[2], r0v[3]);
        o1[idx] = make_float4(r1v[0], r1v[1], r1v[2], r1v[3]);
    }
}

extern "C" void kernel_launch(void* const* d_in, const int* in_sizes, int n_in,
                              void* d_out, int out_size, void* d_ws, size_t ws_size,
                              hipStream_t stream) {
    const float* x     = (const float*)d_in[0];
    const float* W1    = (const float*)d_in[1];
    const float* b1    = (const float*)d_in[2];
    const float* theta = (const float*)d_in[3];
    const float* W2    = (const float*)d_in[4];
    const float* b2    = (const float*)d_in[5];
    float* out = (float*)d_out;

    const int ntok = in_sizes[0] / EMBED;            // 16384
    const int grid = (ntok + TPB - 1) / TPB;         // 2048
    hipLaunchKernelGGL(ffq_kernel, dim3(grid), dim3(BLOCK), 0, stream,
                       x, W1, b1, theta, W2, b2, out, ntok);
}

// Round 4
// 24.420 us; speedup vs baseline: 1.8189x; 1.8189x over previous
//
#include <hip/hip_runtime.h>
#include <math.h>

// FeedForwardQuantum, analytically collapsed circuit:
//   z_j = cos(theta_j) * cos(x.W1_j + b1_j)
//   ex[w] = prod_{j<=w} z_j (w>=1); ex[0] = prod_{j=1..7} z_j
//   out = relu(ex @ W2^T + b2)

constexpr int EMBED = 768;
constexpr int NQ    = 8;
constexpr int BLOCK = 256;            // 4 waves
constexpr int WAVES = 4;
constexpr int TPT   = 4;              // tokens per wave, processed concurrently
constexpr int TPB   = WAVES * TPT;    // 16 tokens/block

typedef float vfloat4 __attribute__((ext_vector_type(4)));  // native vec for nontemporal builtin

__global__ __launch_bounds__(BLOCK, 4) void ffq_kernel(
    const float* __restrict__ x,  const float* __restrict__ W1,
    const float* __restrict__ b1, const float* __restrict__ theta,
    const float* __restrict__ W2, const float* __restrict__ b2,
    float* __restrict__ out, int ntok)
{
    __shared__ float w2t[NQ][EMBED];          // transposed W2 (24 KB)
    __shared__ float zbuf[WAVES][TPT][NQ];    // per-wave z broadcast (512 B)

    const int tid = threadIdx.x;

    // ---- stage W2 transposed: coalesced float4 reads, scalar scatter writes ----
    {
        const float4* W24 = (const float4*)W2;
        for (int i = tid; i < EMBED * NQ / 4; i += BLOCK) {
            const float4 v = W24[i];
            const int f = 4 * i;                 // flat = e*8 + q
            w2t[(f + 0) & 7][(f + 0) >> 3] = v.x;
            w2t[(f + 1) & 7][(f + 1) >> 3] = v.y;
            w2t[(f + 2) & 7][(f + 2) >> 3] = v.z;
            w2t[(f + 3) & 7][(f + 3) >> 3] = v.w;
        }
    }

    const int wave  = tid >> 6;
    const int lane  = tid & 63;
    const int q_own = lane & 7;
    const float costh = __cosf(theta[q_own]);
    const float b1q   = b1[q_own];

    const int t0 = (blockIdx.x * WAVES + wave) * TPT;
    int tk[TPT];
    #pragma unroll
    for (int it = 0; it < TPT; ++it) {
        int t = t0 + it; tk[it] = (t < ntok) ? t : (ntok - 1);   // clamp: benign dup
    }

    // ---- issue all x loads up front (12 KB in flight per wave) ----
    const float4* x4 = (const float4*)x;
    float4 xv[TPT][3];
    #pragma unroll
    for (int it = 0; it < TPT; ++it)
        #pragma unroll
        for (int k = 0; k < 3; ++k)
            xv[it][k] = x4[(size_t)tk[it] * (EMBED / 4) + lane + 64 * k];

    __syncthreads();   // w2t ready

    // ---- GEMM1 partials: W1 from global (L1-resident), shared across tokens ----
    const float4* W14 = (const float4*)W1;
    float acc[TPT][NQ];
    #pragma unroll
    for (int it = 0; it < TPT; ++it)
        #pragma unroll
        for (int q = 0; q < NQ; ++q) acc[it][q] = 0.f;

    #pragma unroll
    for (int k = 0; k < 3; ++k) {
        const int idx = lane + 64 * k;
        #pragma unroll
        for (int q = 0; q < NQ; ++q) {
            const float4 w = W14[q * (EMBED / 4) + idx];
            #pragma unroll
            for (int it = 0; it < TPT; ++it) {
                acc[it][q] = fmaf(xv[it][k].x, w.x, fmaf(xv[it][k].y, w.y,
                             fmaf(xv[it][k].z, w.z, fmaf(xv[it][k].w, w.w, acc[it][q]))));
            }
        }
    }

    // ---- packed reduce: 10 shuffles/token -> lane holds full sum for q = lane&7 ----
    const bool c0 = lane & 1, c1 = lane & 2, c2 = lane & 4;
    float S[TPT];
    #pragma unroll
    for (int it = 0; it < TPT; ++it) {
        float k0 = c0 ? acc[it][1] : acc[it][0], g0 = c0 ? acc[it][0] : acc[it][1];
        float k1 = c0 ? acc[it][3] : acc[it][2], g1 = c0 ? acc[it][2] : acc[it][3];
        float k2 = c0 ? acc[it][5] : acc[it][4], g2 = c0 ? acc[it][4] : acc[it][5];
        float k3 = c0 ? acc[it][7] : acc[it][6], g3 = c0 ? acc[it][6] : acc[it][7];
        float v0 = k0 + __shfl_xor(g0, 1, 64);
        float v1 = k1 + __shfl_xor(g1, 1, 64);
        float v2 = k2 + __shfl_xor(g2, 1, 64);
        float v3 = k3 + __shfl_xor(g3, 1, 64);
        float ka = c1 ? v1 : v0, ga = c1 ? v0 : v1;
        float kb = c1 ? v3 : v2, gb = c1 ? v2 : v3;
        float u0 = ka + __shfl_xor(ga, 2, 64);
        float u1 = kb + __shfl_xor(gb, 2, 64);
        float kc = c2 ? u1 : u0, gc = c2 ? u0 : u1;
        float s  = kc + __shfl_xor(gc, 4, 64);
        s += __shfl_xor(s, 8, 64);
        s += __shfl_xor(s, 16, 64);
        s += __shfl_xor(s, 32, 64);
        S[it] = s;   // full sum of q_in[token it][q_own]
    }

    // ---- one cosf per lane; octet o publishes token (o&3)'s z[q] to LDS ----
    const int osel = (lane >> 3) & (TPT - 1);
    const bool s0 = osel & 1, s1 = osel & 2;
    const float Ssel = s1 ? (s0 ? S[3] : S[2]) : (s0 ? S[1] : S[0]);
    const float zval = costh * __cosf(Ssel + b1q);
    zbuf[wave][osel][q_own] = zval;    // octets o and o+4 write identical values

    // ---- read back sorted z[8] per token (broadcast b128), prefix products ----
    float ex[TPT][NQ];
    #pragma unroll
    for (int it = 0; it < TPT; ++it) {
        const float4 za = ((const float4*)zbuf[wave][it])[0];
        const float4 zb = ((const float4*)zbuf[wave][it])[1];
        const float zq[NQ] = { za.x, za.y, za.z, za.w, zb.x, zb.y, zb.z, zb.w };
        float p = zq[0];
        #pragma unroll
        for (int q = 1; q < NQ; ++q) { p *= zq[q]; ex[it][q] = p; }
        float sfx = zq[1];
        #pragma unroll
        for (int q = 2; q < NQ; ++q) sfx *= zq[q];
        ex[it][0] = sfx;
    }

    // ---- GEMM2 + bias + relu: conflict-free b128 LDS reads, shared across tokens ----
    const float4* b24 = (const float4*)b2;
    #pragma unroll
    for (int k = 0; k < 3; ++k) {
        const int idx = lane + 64 * k;
        const float4 bb = b24[idx];
        float4 r[TPT];
        #pragma unroll
        for (int it = 0; it < TPT; ++it) r[it] = bb;
        #pragma unroll
        for (int q = 0; q < NQ; ++q) {
            const float4 w = ((const float4*)&w2t[q][0])[idx];
            #pragma unroll
            for (int it = 0; it < TPT; ++it) {
                r[it].x = fmaf(ex[it][q], w.x, r[it].x);
                r[it].y = fmaf(ex[it][q], w.y, r[it].y);
                r[it].z = fmaf(ex[it][q], w.z, r[it].z);
                r[it].w = fmaf(ex[it][q], w.w, r[it].w);
            }
        }
        #pragma unroll
        for (int it = 0; it < TPT; ++it) {
            vfloat4 o = { fmaxf(r[it].x, 0.f), fmaxf(r[it].y, 0.f),
                          fmaxf(r[it].z, 0.f), fmaxf(r[it].w, 0.f) };
            __builtin_nontemporal_store(o, (vfloat4*)(out + (size_t)tk[it] * EMBED) + idx);
        }
    }
}

extern "C" void kernel_launch(void* const* d_in, const int* in_sizes, int n_in,
                              void* d_out, int out_size, void* d_ws, size_t ws_size,
                              hipStream_t stream) {
    const float* x     = (const float*)d_in[0];
    const float* W1    = (const float*)d_in[1];
    const float* b1    = (const float*)d_in[2];
    const float* theta = (const float*)d_in[3];
    const float* W2    = (const float*)d_in[4];
    const float* b2    = (const float*)d_in[5];
    float* out = (float*)d_out;

    const int ntok = in_sizes[0] / EMBED;          // 16384
    const int grid = (ntok + TPB - 1) / TPB;       // 1024 = 4 blocks/CU exactly
    hipLaunchKernelGGL(ffq_kernel, dim3(grid), dim3(BLOCK), 0, stream,
                       x, W1, b1, theta, W2, b2, out, ntok);
}